// Round 4
// baseline (248.115 us; speedup 1.0000x reference)
//
#include <hip/hip_runtime.h>
#include <stdint.h>

// BinaryLinearWscales: out[m,n] = wscale[n] * (x @ sign(W)^T)[m,n] + wbias[n] * rowsum(x)[m]
// M = B*S = 4096, N = DOUT = 4096, K = DIN = 4096.
// Round 4: i8 MFMA BK=64, double-buffered LDS prefetch (distance 1, one barrier/iter),
// fused prep kernel.

#define MDIM 4096
#define NDIM 4096
#define KDIM 4096

typedef int int4v __attribute__((ext_vector_type(4)));

__device__ __forceinline__ int pack4_rn(float a, float b, float c, float d, float inv) {
  int ia = __float2int_rn(a * inv) & 0xff;
  int ib = __float2int_rn(b * inv) & 0xff;
  int ic = __float2int_rn(c * inv) & 0xff;
  int id = __float2int_rn(d * inv) & 0xff;
  return ia | (ib << 8) | (ic << 16) | (id << 24);
}

__device__ __forceinline__ int sgn8(float v) {
  return (v > 0.f) ? 1 : ((v < 0.f) ? 0xff : 0);
}

// ---------------- fused prep ----------------
// blocks [0,4096): per-row x quant (i8 symmetric) + rowsum + rowscale
// blocks [4096,5120): streaming sign(W) -> i8, 16 KB per block
__global__ __launch_bounds__(256) void prep_kernel(
    const float* __restrict__ x, const float* __restrict__ w,
    char* __restrict__ xq, char* __restrict__ wsg,
    float* __restrict__ xscale, float* __restrict__ sumx) {
  const int b = blockIdx.x;
  const int tid = threadIdx.x;
  if (b < MDIM) {
    const int row = b;
    const float4* xr = (const float4*)(x + (size_t)row * KDIM);
    float4 v[4];
    float s = 0.f, amax = 0.f;
#pragma unroll
    for (int u = 0; u < 4; ++u) {
      v[u] = xr[u * 256 + tid];
      s += v[u].x + v[u].y + v[u].z + v[u].w;
      amax = fmaxf(amax, fmaxf(fmaxf(fabsf(v[u].x), fabsf(v[u].y)),
                               fmaxf(fabsf(v[u].z), fabsf(v[u].w))));
    }
#pragma unroll
    for (int off = 32; off > 0; off >>= 1) {
      s += __shfl_down(s, off, 64);
      amax = fmaxf(amax, __shfl_down(amax, off, 64));
    }
    __shared__ float rs[4], rm[4], bcast;
    if ((tid & 63) == 0) { rs[tid >> 6] = s; rm[tid >> 6] = amax; }
    __syncthreads();
    if (tid == 0) {
      sumx[row] = rs[0] + rs[1] + rs[2] + rs[3];
      float mt = fmaxf(fmaxf(rm[0], rm[1]), fmaxf(rm[2], rm[3]));
      xscale[row] = mt * (1.f / 127.f);
      bcast = (mt > 0.f) ? 127.f / mt : 0.f;
    }
    __syncthreads();
    const float inv = bcast;
    int* xo = (int*)(xq + (size_t)row * KDIM);
#pragma unroll
    for (int u = 0; u < 4; ++u)
      xo[u * 256 + tid] = pack4_rn(v[u].x, v[u].y, v[u].z, v[u].w, inv);
  } else {
    const size_t base = (size_t)(b - MDIM) * (256 * 4);
    const float4* wr = (const float4*)w;
    int* wo = (int*)wsg;
#pragma unroll
    for (int u = 0; u < 4; ++u) {
      size_t i = base + u * 256 + tid;
      float4 v = wr[i];
      wo[i] = sgn8(v.x) | (sgn8(v.y) << 8) | (sgn8(v.z) << 16) | (sgn8(v.w) << 24);
    }
  }
}

// ---------------- main GEMM: C = A (MxK i8) * Bs^T (Bs is NxK i8) ----------------
// 128x128 tile, BK=64, 4 waves (2x2) x 4x4 frags of mfma_i32_16x16x64_i8.
// Double-buffered LDS (2 x 16 KB), prefetch distance 1, ONE barrier per K-iter:
//   barrier (tile k ready; buf k-1 readers done) -> issue loads tile k+1 -> compute k
// XOR swizzle (64B rows = 4 x 16B blocks): phys = logical ^ ((row>>1)&3) -> 0 conflicts (R2).
__global__ __launch_bounds__(256) void gemm_bin_i8_kernel(
    const char* __restrict__ A, const char* __restrict__ Bs,
    const float* __restrict__ wscale, const float* __restrict__ wbias,
    const float* __restrict__ xscale, const float* __restrict__ sumx,
    float* __restrict__ C) {
  __shared__ __align__(16) char sA0[128 * 64], sA1[128 * 64];
  __shared__ __align__(16) char sB0[128 * 64], sB1[128 * 64];

  const int bn = blockIdx.x & 31;
  const int bm = blockIdx.x >> 5;
  const int tm0 = bm * 128, tn0 = bn * 128;
  const int tid = threadIdx.x;
  const int lane = tid & 63, wave = tid >> 6;
  const int quad = lane >> 4, l16 = lane & 15;
  const int wmo = (wave >> 1) * 64, wno = (wave & 1) * 64;

  int4v acc[4][4];
  const int4v zero4 = {0, 0, 0, 0};
#pragma unroll
  for (int i = 0; i < 4; ++i)
#pragma unroll
    for (int j = 0; j < 4; ++j) acc[i][j] = zero4;

  // staging geometry: 16B unit u = q*256+tid; row=u>>2, pblk=u&3, lblk=pblk^((row>>1)&3)
  int st_row[2], st_lblk[2];
#pragma unroll
  for (int q = 0; q < 2; ++q) {
    int u = q * 256 + tid;
    st_row[q] = u >> 2;
    st_lblk[q] = (u & 3) ^ ((st_row[q] >> 1) & 3);
  }
  // per-thread global row bases (loop-invariant)
  const char* gA0 = A  + (size_t)(tm0 + st_row[0]) * KDIM + st_lblk[0] * 16;
  const char* gA1 = A  + (size_t)(tm0 + st_row[1]) * KDIM + st_lblk[1] * 16;
  const char* gB0 = Bs + (size_t)(tn0 + st_row[0]) * KDIM + st_lblk[0] * 16;
  const char* gB1 = Bs + (size_t)(tn0 + st_row[1]) * KDIM + st_lblk[1] * 16;
  const int ld0 = tid * 16, ld1 = 4096 + tid * 16;

  // fragment-read LDS offsets (loop-invariant)
  int aOff[4], bOff[4];
#pragma unroll
  for (int i = 0; i < 4; ++i) {
    int r = wmo + i * 16 + l16;
    aOff[i] = r * 64 + (quad ^ ((r >> 1) & 3)) * 16;
  }
#pragma unroll
  for (int j = 0; j < 4; ++j) {
    int r = wno + j * 16 + l16;
    bOff[j] = r * 64 + (quad ^ ((r >> 1) & 3)) * 16;
  }

#define STAGE(dstA, dstB, kofs)                                                  \
  do {                                                                           \
    __builtin_amdgcn_global_load_lds(                                            \
        (const __attribute__((address_space(1))) void*)(gA0 + (kofs)),           \
        (__attribute__((address_space(3))) void*)((dstA) + ld0), 16, 0, 0);      \
    __builtin_amdgcn_global_load_lds(                                            \
        (const __attribute__((address_space(1))) void*)(gA1 + (kofs)),           \
        (__attribute__((address_space(3))) void*)((dstA) + ld1), 16, 0, 0);      \
    __builtin_amdgcn_global_load_lds(                                            \
        (const __attribute__((address_space(1))) void*)(gB0 + (kofs)),           \
        (__attribute__((address_space(3))) void*)((dstB) + ld0), 16, 0, 0);      \
    __builtin_amdgcn_global_load_lds(                                            \
        (const __attribute__((address_space(1))) void*)(gB1 + (kofs)),           \
        (__attribute__((address_space(3))) void*)((dstB) + ld1), 16, 0, 0);      \
  } while (0)

#define COMPUTE(srcA, srcB)                                                      \
  do {                                                                           \
    int4v af[4], bfr[4];                                                         \
    _Pragma("unroll") for (int i = 0; i < 4; ++i)                                \
        af[i] = *(const int4v*)((srcA) + aOff[i]);                               \
    _Pragma("unroll") for (int j = 0; j < 4; ++j)                                \
        bfr[j] = *(const int4v*)((srcB) + bOff[j]);                              \
    _Pragma("unroll") for (int i = 0; i < 4; ++i)                                \
        _Pragma("unroll") for (int j = 0; j < 4; ++j)                            \
            acc[i][j] = __builtin_amdgcn_mfma_i32_16x16x64_i8(af[i], bfr[j],     \
                                                              acc[i][j], 0, 0, 0);\
  } while (0)

  STAGE(sA0, sB0, 0);
  for (int kt = 0; kt < KDIM; kt += 128) {
    __syncthreads();                       // buf0 (tile kt) ready; buf1 readers done
    if (kt + 64 < KDIM) STAGE(sA1, sB1, kt + 64);
    COMPUTE(sA0, sB0);
    __syncthreads();                       // buf1 (tile kt+64) ready; buf0 readers done
    if (kt + 128 < KDIM) STAGE(sA0, sB0, kt + 128);
    COMPUTE(sA1, sB1);
  }
#undef STAGE
#undef COMPUTE

  // epilogue: C[m,n] = wscale[n]*xscale[m]*acc + wbias[n]*sumx[m]
  float wsv[4], wbv[4];
#pragma unroll
  for (int j = 0; j < 4; ++j) {
    int n = tn0 + wno + j * 16 + l16;
    wsv[j] = wscale[n];
    wbv[j] = wbias[n];
  }
#pragma unroll
  for (int i = 0; i < 4; ++i) {
#pragma unroll
    for (int r = 0; r < 4; ++r) {
      int m = tm0 + wmo + i * 16 + quad * 4 + r;   // C/D layout: row = quad*4 + reg
      float xs = xscale[m];
      float sx = sumx[m];
      float* crow = C + (size_t)m * NDIM + tn0 + wno + l16;  // col = lane&15
#pragma unroll
      for (int j = 0; j < 4; ++j) {
        crow[j * 16] = wsv[j] * xs * (float)acc[i][j][r] + wbv[j] * sx;
      }
    }
  }
}

extern "C" void kernel_launch(void* const* d_in, const int* in_sizes, int n_in,
                              void* d_out, int out_size, void* d_ws, size_t ws_size,
                              hipStream_t stream) {
  const float* x      = (const float*)d_in[0];
  const float* weight = (const float*)d_in[1];
  const float* wscale = (const float*)d_in[2];
  const float* wbias  = (const float*)d_in[3];
  float* out = (float*)d_out;

  char* xq  = (char*)d_ws;
  char* wsg = xq + (size_t)MDIM * KDIM;
  float* xscale = (float*)(wsg + (size_t)NDIM * KDIM);
  float* sumx   = xscale + MDIM;

  prep_kernel<<<MDIM + (NDIM * KDIM) / (16 * 256), 256, 0, stream>>>(
      x, weight, xq, wsg, xscale, sumx);
  gemm_bin_i8_kernel<<<(MDIM / 128) * (NDIM / 128), 256, 0, stream>>>(
      xq, wsg, wscale, wbias, xscale, sumx, out);
}

// Round 5
// 244.572 us; speedup vs baseline: 1.0145x; 1.0145x over previous
//
#include <hip/hip_runtime.h>
#include <stdint.h>

// BinaryLinearWscales: out[m,n] = wscale[n] * (x @ sign(W)^T)[m,n] + wbias[n] * rowsum(x)[m]
// M = B*S = 4096, N = DOUT = 4096, K = DIN = 4096.
// Round 5: i8 MFMA BK=64, 3-buffer ring (prefetch distance 2), AITER-style
// manual "s_waitcnt vmcnt(4); s_barrier" so the newest tile's loads stay in
// flight across the barrier (never vmcnt(0) until the tail).

#define MDIM 4096
#define NDIM 4096
#define KDIM 4096

typedef int int4v __attribute__((ext_vector_type(4)));

__device__ __forceinline__ int pack4_rn(float a, float b, float c, float d, float inv) {
  int ia = __float2int_rn(a * inv) & 0xff;
  int ib = __float2int_rn(b * inv) & 0xff;
  int ic = __float2int_rn(c * inv) & 0xff;
  int id = __float2int_rn(d * inv) & 0xff;
  return ia | (ib << 8) | (ic << 16) | (id << 24);
}

__device__ __forceinline__ int sgn8(float v) {
  return (v > 0.f) ? 1 : ((v < 0.f) ? 0xff : 0);
}

// ---------------- fused prep ----------------
// blocks [0,4096): per-row x quant (i8 symmetric) + rowsum + rowscale
// blocks [4096,5120): streaming sign(W) -> i8
__global__ __launch_bounds__(256) void prep_kernel(
    const float* __restrict__ x, const float* __restrict__ w,
    char* __restrict__ xq, char* __restrict__ wsg,
    float* __restrict__ xscale, float* __restrict__ sumx) {
  const int b = blockIdx.x;
  const int tid = threadIdx.x;
  if (b < MDIM) {
    const int row = b;
    const float4* xr = (const float4*)(x + (size_t)row * KDIM);
    float4 v[4];
    float s = 0.f, amax = 0.f;
#pragma unroll
    for (int u = 0; u < 4; ++u) {
      v[u] = xr[u * 256 + tid];
      s += v[u].x + v[u].y + v[u].z + v[u].w;
      amax = fmaxf(amax, fmaxf(fmaxf(fabsf(v[u].x), fabsf(v[u].y)),
                               fmaxf(fabsf(v[u].z), fabsf(v[u].w))));
    }
#pragma unroll
    for (int off = 32; off > 0; off >>= 1) {
      s += __shfl_down(s, off, 64);
      amax = fmaxf(amax, __shfl_down(amax, off, 64));
    }
    __shared__ float rs[4], rm[4], bcast;
    if ((tid & 63) == 0) { rs[tid >> 6] = s; rm[tid >> 6] = amax; }
    __syncthreads();
    if (tid == 0) {
      sumx[row] = rs[0] + rs[1] + rs[2] + rs[3];
      float mt = fmaxf(fmaxf(rm[0], rm[1]), fmaxf(rm[2], rm[3]));
      xscale[row] = mt * (1.f / 127.f);
      bcast = (mt > 0.f) ? 127.f / mt : 0.f;
    }
    __syncthreads();
    const float inv = bcast;
    int* xo = (int*)(xq + (size_t)row * KDIM);
#pragma unroll
    for (int u = 0; u < 4; ++u)
      xo[u * 256 + tid] = pack4_rn(v[u].x, v[u].y, v[u].z, v[u].w, inv);
  } else {
    const size_t base = (size_t)(b - MDIM) * (256 * 4);
    const float4* wr = (const float4*)w;
    int* wo = (int*)wsg;
#pragma unroll
    for (int u = 0; u < 4; ++u) {
      size_t i = base + u * 256 + tid;
      float4 v = wr[i];
      wo[i] = sgn8(v.x) | (sgn8(v.y) << 8) | (sgn8(v.z) << 16) | (sgn8(v.w) << 24);
    }
  }
}

// ---------------- main GEMM: C = A (MxK i8) * Bs^T (Bs is NxK i8) ----------------
// 128x128 tile, BK=64, 4 waves (2x2) x 4x4 frags of mfma_i32_16x16x64_i8.
// Ring of 3 LDS buffers (prefetch distance 2). Per iter:
//   s_waitcnt vmcnt(4)  (tile i's 4 loads done; tile i+1's 4 stay in flight)
//   s_barrier           (all threads' tile-i loads landed)
//   STAGE(tile i+2)  ->  COMPUTE(tile i)
// Overwrite hazard (buf i+2 == buf i-1): compute(i-1)'s ds_reads were consumed
// by its MFMAs (lgkm drained) before barrier i, so the DMA writes can't race them.
// XOR swizzle (64B rows = 4 x 16B blocks): phys = logical ^ ((row>>1)&3) -> 0 conflicts.
__global__ __launch_bounds__(256) void gemm_bin_i8_kernel(
    const char* __restrict__ A, const char* __restrict__ Bs,
    const float* __restrict__ wscale, const float* __restrict__ wbias,
    const float* __restrict__ xscale, const float* __restrict__ sumx,
    float* __restrict__ C) {
  __shared__ __align__(16) char sA0[128 * 64], sA1[128 * 64], sA2[128 * 64];
  __shared__ __align__(16) char sB0[128 * 64], sB1[128 * 64], sB2[128 * 64];

  const int bn = blockIdx.x & 31;
  const int bm = blockIdx.x >> 5;
  const int tm0 = bm * 128, tn0 = bn * 128;
  const int tid = threadIdx.x;
  const int lane = tid & 63, wave = tid >> 6;
  const int quad = lane >> 4, l16 = lane & 15;
  const int wmo = (wave >> 1) * 64, wno = (wave & 1) * 64;

  int4v acc[4][4];
  const int4v zero4 = {0, 0, 0, 0};
#pragma unroll
  for (int i = 0; i < 4; ++i)
#pragma unroll
    for (int j = 0; j < 4; ++j) acc[i][j] = zero4;

  // staging geometry: 16B unit u = q*256+tid; row=u>>2, pblk=u&3, lblk=pblk^((row>>1)&3)
  int st_row[2], st_lblk[2];
#pragma unroll
  for (int q = 0; q < 2; ++q) {
    int u = q * 256 + tid;
    st_row[q] = u >> 2;
    st_lblk[q] = (u & 3) ^ ((st_row[q] >> 1) & 3);
  }
  const char* gA0 = A  + (size_t)(tm0 + st_row[0]) * KDIM + st_lblk[0] * 16;
  const char* gA1 = A  + (size_t)(tm0 + st_row[1]) * KDIM + st_lblk[1] * 16;
  const char* gB0 = Bs + (size_t)(tn0 + st_row[0]) * KDIM + st_lblk[0] * 16;
  const char* gB1 = Bs + (size_t)(tn0 + st_row[1]) * KDIM + st_lblk[1] * 16;
  const int ld0 = tid * 16, ld1 = 4096 + tid * 16;

  // fragment-read LDS offsets (loop-invariant)
  int aOff[4], bOff[4];
#pragma unroll
  for (int i = 0; i < 4; ++i) {
    int r = wmo + i * 16 + l16;
    aOff[i] = r * 64 + (quad ^ ((r >> 1) & 3)) * 16;
  }
#pragma unroll
  for (int j = 0; j < 4; ++j) {
    int r = wno + j * 16 + l16;
    bOff[j] = r * 64 + (quad ^ ((r >> 1) & 3)) * 16;
  }

#define STAGE(dstA, dstB, kofs)                                                  \
  do {                                                                           \
    __builtin_amdgcn_global_load_lds(                                            \
        (const __attribute__((address_space(1))) void*)(gA0 + (kofs)),           \
        (__attribute__((address_space(3))) void*)((dstA) + ld0), 16, 0, 0);      \
    __builtin_amdgcn_global_load_lds(                                            \
        (const __attribute__((address_space(1))) void*)(gA1 + (kofs)),           \
        (__attribute__((address_space(3))) void*)((dstA) + ld1), 16, 0, 0);      \
    __builtin_amdgcn_global_load_lds(                                            \
        (const __attribute__((address_space(1))) void*)(gB0 + (kofs)),           \
        (__attribute__((address_space(3))) void*)((dstB) + ld0), 16, 0, 0);      \
    __builtin_amdgcn_global_load_lds(                                            \
        (const __attribute__((address_space(1))) void*)(gB1 + (kofs)),           \
        (__attribute__((address_space(3))) void*)((dstB) + ld1), 16, 0, 0);      \
  } while (0)

#define COMPUTE(srcA, srcB)                                                      \
  do {                                                                           \
    int4v af[4], bfr[4];                                                         \
    _Pragma("unroll") for (int i = 0; i < 4; ++i)                                \
        af[i] = *(const int4v*)((srcA) + aOff[i]);                               \
    _Pragma("unroll") for (int j = 0; j < 4; ++j)                                \
        bfr[j] = *(const int4v*)((srcB) + bOff[j]);                              \
    _Pragma("unroll") for (int i = 0; i < 4; ++i)                                \
        _Pragma("unroll") for (int j = 0; j < 4; ++j)                            \
            acc[i][j] = __builtin_amdgcn_mfma_i32_16x16x64_i8(af[i], bfr[j],     \
                                                              acc[i][j], 0, 0, 0);\
  } while (0)

// wait for all but the newest 4 loads (tile i done, tile i+1 in flight), then barrier
#define SYNC_KEEP4() asm volatile("s_waitcnt vmcnt(4)\n\ts_barrier" ::: "memory")
#define SYNC_ALL()   asm volatile("s_waitcnt vmcnt(0)\n\ts_barrier" ::: "memory")

// full pipelined iteration: compute tile i from (cA,cB), stage tile i+2 into (pA,pB)
#define ITER(cA, cB, pA, pB, kofs_next)                                          \
  do {                                                                           \
    SYNC_KEEP4();                                                                \
    STAGE(pA, pB, (kofs_next));                                                  \
    COMPUTE(cA, cB);                                                             \
  } while (0)

  STAGE(sA0, sB0, 0);
  STAGE(sA1, sB1, 64);
  // tiles t = kt/64, t = 0..63. Main: i = 0..61 (stage t_{i+2}); tail: 62, 63.
  for (int i = 0; i < 60; i += 3) {
    ITER(sA0, sB0, sA2, sB2, (i + 2) * 64);
    ITER(sA1, sB1, sA0, sB0, (i + 3) * 64);
    ITER(sA2, sB2, sA1, sB1, (i + 4) * 64);
  }
  ITER(sA0, sB0, sA2, sB2, 62 * 64);   // i = 60
  ITER(sA1, sB1, sA0, sB0, 63 * 64);   // i = 61
  SYNC_KEEP4();                        // i = 62: t62 landed, t63 in flight
  COMPUTE(sA2, sB2);
  SYNC_ALL();                          // i = 63: drain t63
  COMPUTE(sA0, sB0);
#undef ITER
#undef SYNC_KEEP4
#undef SYNC_ALL
#undef STAGE
#undef COMPUTE

  // epilogue: C[m,n] = wscale[n]*xscale[m]*acc + wbias[n]*sumx[m]
  float wsv[4], wbv[4];
#pragma unroll
  for (int j = 0; j < 4; ++j) {
    int n = tn0 + wno + j * 16 + l16;
    wsv[j] = wscale[n];
    wbv[j] = wbias[n];
  }
#pragma unroll
  for (int i = 0; i < 4; ++i) {
#pragma unroll
    for (int r = 0; r < 4; ++r) {
      int m = tm0 + wmo + i * 16 + quad * 4 + r;   // C/D layout: row = quad*4 + reg
      float xs = xscale[m];
      float sx = sumx[m];
      float* crow = C + (size_t)m * NDIM + tn0 + wno + l16;  // col = lane&15
#pragma unroll
      for (int j = 0; j < 4; ++j) {
        crow[j * 16] = wsv[j] * xs * (float)acc[i][j][r] + wbv[j] * sx;
      }
    }
  }
}

extern "C" void kernel_launch(void* const* d_in, const int* in_sizes, int n_in,
                              void* d_out, int out_size, void* d_ws, size_t ws_size,
                              hipStream_t stream) {
  const float* x      = (const float*)d_in[0];
  const float* weight = (const float*)d_in[1];
  const float* wscale = (const float*)d_in[2];
  const float* wbias  = (const float*)d_in[3];
  float* out = (float*)d_out;

  char* xq  = (char*)d_ws;
  char* wsg = xq + (size_t)MDIM * KDIM;
  float* xscale = (float*)(wsg + (size_t)NDIM * KDIM);
  float* sumx   = xscale + MDIM;

  prep_kernel<<<MDIM + (NDIM * KDIM) / (16 * 256), 256, 0, stream>>>(
      x, weight, xq, wsg, xscale, sumx);
  gemm_bin_i8_kernel<<<(MDIM / 128) * (NDIM / 128), 256, 0, stream>>>(
      xq, wsg, wscale, wbias, xscale, sumx, out);
}